// Round 11
// baseline (234.571 us; speedup 1.0000x reference)
//
#include <hip/hip_runtime.h>
#include <hip/hip_bf16.h>
#include <stdint.h>

typedef unsigned short u16_t;
typedef unsigned int   u32_t;

#define B_ROWS  16384
#define D_IN    1024
#define D_OUT   512
#define NEXP    16
#define CNT_STRIDE 16   // pad each expert counter to its own 64B line
#define EPSF    2.2204460492503131e-16f

using short8  = __attribute__((ext_vector_type(8))) short;
using floatx4 = __attribute__((ext_vector_type(4))) float;

__device__ __forceinline__ u16_t f2bf(float f) {
    u32_t u = __float_as_uint(f);
    u += 0x7fffu + ((u >> 16) & 1u);        // round-to-nearest-even
    return (u16_t)(u >> 16);
}

// async global->LDS, 16B per lane. Global addr is per-lane; LDS dest is the
// wave-uniform base (HW adds lane*16).
__device__ __forceinline__ void gload_lds16(const void* g, void* l) {
    __builtin_amdgcn_global_load_lds(
        (const __attribute__((address_space(1))) void*)g,
        (__attribute__((address_space(3))) void*)l, 16, 0, 0);
}

// ---------------------------------------------------------------------------
// Prep: [0..63] transpose w_router -> wrT [E][D_IN] f32; [64] zero counts;
// [65..4160] w_experts [e][k][n] f32 -> wT [e][n][k] bf16 (tier3 only).
// ---------------------------------------------------------------------------
__global__ __launch_bounds__(256) void prep_kernel(
        const float* __restrict__ wr, float* __restrict__ wrT,
        const float* __restrict__ we, u16_t* __restrict__ wT,
        int* __restrict__ counts) {
    int b = blockIdx.x, t = threadIdx.x;
    if (b < 64) {
        int i = b * 256 + t;                 // i = e*D_IN + d
        int e = i >> 10, d = i & 1023;
        wrT[i] = wr[d * NEXP + e];
    } else if (b == 64) {
        counts[t] = 0;                       // 256 ints = 1024 B
    } else {
        int bb = b - 65;
        int e  = bb >> 8;
        int k0 = ((bb >> 1) & 127) * 8;
        int n  = (bb & 1) * 256 + t;
        const float* src = we + ((size_t)e * D_IN + k0) * D_OUT + n;
        union { u16_t us[8]; uint4 v; } p;
        #pragma unroll
        for (int j = 0; j < 8; ++j) p.us[j] = f2bf(src[(size_t)j * D_OUT]);
        *(uint4*)(wT + ((size_t)e * D_OUT + n) * D_IN + k0) = p.v;
    }
}

// ---------------------------------------------------------------------------
// Router v11. v10 still showed VGPR=52: the allocator remats x from memory
// across the expert-phase barriers, so the hoist never sticks, and the
// 2048-block grid ran 2 occupancy batches with 128 ds_read/thread.
// v11 phases over the D-RANGE instead of experts: stage all 16 experts' w
// for d-half (32 KB), consume with R=2 row blocking (each wsh read reused
// across 2 rows -> ds_read per row HALVED), then restage the other half.
// Per phase only xv[2][4] (32 VGPR) is live -- a short-lived budget the
// allocator accepts -- pinned with "+v" (remat illegal). 16 rows/block ->
// 1024 blocks = exactly 4 blocks/CU = ONE dispatch batch. Per-lane d-order
// (c*4 + {0,128,...,896}) identical to v10 -> bitwise-identical logits.
// ---------------------------------------------------------------------------
__global__ __launch_bounds__(256) void router_kernel(
        const float* __restrict__ x, const float* __restrict__ wrT,
        int* __restrict__ counts, int* __restrict__ rowlist,
        float* __restrict__ gatelist, u16_t* __restrict__ xb) {
    __shared__ float wsh[NEXP * 512];       // 32 KB: ALL experts, half d-range
    __shared__ int hist[NEXP], base[NEXP], hist2[NEXP];
    __shared__ unsigned char eidx_sh[16][2];
    __shared__ float g_sh[16][2];

    int t = threadIdx.x;
    if (t < NEXP) { hist[t] = 0; hist2[t] = 0; }

    int lane = t & 63, wv = t >> 6;
    int lr = t >> 5, c = t & 31;            // row-pair group, d-slice
    int row0 = blockIdx.x * 16 + lr * 2;

    float acc[2][NEXP];
    #pragma unroll
    for (int rr = 0; rr < 2; ++rr)
        #pragma unroll
        for (int e = 0; e < NEXP; ++e) acc[rr][e] = 0.f;

    #pragma unroll
    for (int ph = 0; ph < 2; ++ph) {
        if (ph) __syncthreads();            // all waves done reading prev half
        // stage w half: slot s = r*256+wv*64+lane; e=s>>7, d4=s&127.
        // 16 e x 512 floats = 32 KB, 8 rounds x 1 KB/wave, async, no VGPRs.
        #pragma unroll
        for (int r = 0; r < 8; ++r) {
            int s  = r * 256 + wv * 64 + lane;
            int e  = s >> 7, d4 = s & 127;
            gload_lds16(wrT + e * D_IN + ph * 512 + d4 * 4,
                        (char*)wsh + r * 4096 + wv * 1024);
        }
        // x for this phase: 2 rows x 4 float4 (32 VGPR, short-lived), pinned
        float4 xv[2][4];
        #pragma unroll
        for (int rr = 0; rr < 2; ++rr)
            #pragma unroll
            for (int i = 0; i < 4; ++i)
                xv[rr][i] = *(const float4*)(x + (size_t)(row0 + rr) * D_IN
                                               + ph * 512 + c * 4 + i * 128);
        #pragma unroll
        for (int rr = 0; rr < 2; ++rr)
            #pragma unroll
            for (int i = 0; i < 4; ++i)
                asm volatile("" : "+v"(xv[rr][i].x), "+v"(xv[rr][i].y),
                                  "+v"(xv[rr][i].z), "+v"(xv[rr][i].w));
        if (xb) {                           // fused bf16 emit, 256B/row/instr
            #pragma unroll
            for (int rr = 0; rr < 2; ++rr)
                #pragma unroll
                for (int i = 0; i < 4; ++i) {
                    uint2 pk;
                    pk.x = (u32_t)f2bf(xv[rr][i].x) | ((u32_t)f2bf(xv[rr][i].y) << 16);
                    pk.y = (u32_t)f2bf(xv[rr][i].z) | ((u32_t)f2bf(xv[rr][i].w) << 16);
                    *(uint2*)(xb + (size_t)(row0 + rr) * D_IN
                                 + ph * 512 + c * 4 + i * 128) = pk;
                }
        }
        __syncthreads();                    // wsh ready (vmcnt(0) before barrier)
        #pragma unroll
        for (int i = 0; i < 4; ++i) {
            int fo = c * 4 + i * 128;       // float offset in half-row
            #pragma unroll
            for (int e = 0; e < NEXP; ++e) {
                float4 wv4 = *(const float4*)(&wsh[e * 512 + fo]);
                #pragma unroll
                for (int rr = 0; rr < 2; ++rr) {
                    acc[rr][e] += xv[rr][i].x * wv4.x;
                    acc[rr][e] += xv[rr][i].y * wv4.y;
                    acc[rr][e] += xv[rr][i].z * wv4.z;
                    acc[rr][e] += xv[rr][i].w * wv4.w;
                }
            }
        }
    }

    // butterfly reduce over the 32 d-slice lanes (c = low 5 lane bits)
    #pragma unroll
    for (int rr = 0; rr < 2; ++rr)
        #pragma unroll
        for (int e = 0; e < NEXP; ++e) {
            acc[rr][e] += __shfl_xor(acc[rr][e], 1);
            acc[rr][e] += __shfl_xor(acc[rr][e], 2);
            acc[rr][e] += __shfl_xor(acc[rr][e], 4);
            acc[rr][e] += __shfl_xor(acc[rr][e], 8);
            acc[rr][e] += __shfl_xor(acc[rr][e], 16);
        }
    if (c == 0) {
        #pragma unroll
        for (int rr = 0; rr < 2; ++rr) {
            // top-2, stable (lower index wins ties) == jax.lax.top_k
            int i1 = 0; float v1 = acc[rr][0];
            #pragma unroll
            for (int e = 1; e < NEXP; ++e) if (acc[rr][e] > v1) { v1 = acc[rr][e]; i1 = e; }
            int i2 = -1; float v2 = -3.0e38f;
            #pragma unroll
            for (int e = 0; e < NEXP; ++e) if (e != i1 && acc[rr][e] > v2) { v2 = acc[rr][e]; i2 = e; }
            float ed = expf(v2 - v1);       // <= 1
            float s = 1.0f + ed;
            int lrow = lr * 2 + rr;
            eidx_sh[lrow][0] = (unsigned char)i1; g_sh[lrow][0] = 1.0f / s;
            eidx_sh[lrow][1] = (unsigned char)i2; g_sh[lrow][1] = ed / s;
            atomicAdd(&hist[i1], 1);
            atomicAdd(&hist[i2], 1);
        }
    }
    __syncthreads();
    if (t < NEXP) base[t] = atomicAdd(&counts[t * CNT_STRIDE], hist[t]);
    __syncthreads();
    if (t < 32) {
        int r = t >> 1, sl = t & 1;
        int e = eidx_sh[r][sl];
        int pos = base[e] + atomicAdd(&hist2[e], 1);
        rowlist[e * B_ROWS + pos] = ((blockIdx.x * 16 + r) << 1) | sl;
        gatelist[e * B_ROWS + pos] = g_sh[r][sl];
    }
}

// ---------------------------------------------------------------------------
// Grouped expert GEMM, m97 structure: 128x128 tile, BK=64, 16B
// global_load_lds staging into linear LDS [128][64] bf16, XOR swizzle
// slot^=(row&7) applied to BOTH the staging global source and the ds_read
// (involution -> linear dest stays correct). 2x2 waves, 4x4 16x16x32 frags.
// 1-D grid with XCD-aware decode: bid%8 = XCD owns experts {2x, 2x+1} so
// each expert's 1 MB B-panel stays L2-resident and A-tiles are XCD-local.
// ---------------------------------------------------------------------------
template<bool USE_CONTRIB>
__global__ __launch_bounds__(256) void moe_gemm_bf16(
        const u16_t* __restrict__ xb, const u16_t* __restrict__ wT,
        const int* __restrict__ counts, const int* __restrict__ rowlist,
        const float* __restrict__ gatelist,
        float* __restrict__ out, float* __restrict__ contrib) {
    int bid = blockIdx.x;
    int s   = bid >> 3;                       // 0..1023
    int e   = ((bid & 7) << 1) | (s >> 9);    // 2 experts per XCD class
    s &= 511;
    int tx = s & 3, ty = s >> 2;
    int n_e = counts[e * CNT_STRIDE];
    if (ty * 128 >= n_e) return;
    int n0 = tx * 128;

    __shared__ u16_t Ash[128 * 64];   // linear [row][64k] bf16, 16 KB
    __shared__ u16_t Bsh[128 * 64];   // linear [n][64k]  bf16, 16 KB
    __shared__ int   rid_sh[128];
    __shared__ float gt_sh[128];

    int t = threadIdx.x;
    if (t < 128) {
        int gi = ty * 128 + t;
        int v = 0; float g = 0.f;
        if (gi < n_e) { v = rowlist[e * B_ROWS + gi]; g = gatelist[e * B_ROWS + gi]; }
        rid_sh[t] = v; gt_sh[t] = g;
    }
    __syncthreads();

    int lane = t & 63, wv = t >> 6;

    // staging geometry: round r covers bytes [r*4096 + wv*1024 + lane*16).
    // 16B-slot id i = r*256 + wv*64 + lane; row = i>>3; phys slot = i&7;
    // source fetches logical slot (i&7)^(row&7)  (pre-swizzled source).
    const u16_t* asrc[4];
    const u16_t* bsrc[4];
    #pragma unroll
    for (int r = 0; r < 4; ++r) {
        int i   = r * 256 + wv * 64 + lane;
        int row = i >> 3;
        int ss  = (i & 7) ^ (row & 7);
        asrc[r] = xb + (size_t)(rid_sh[row] >> 1) * D_IN + ss * 8;
        bsrc[r] = wT + ((size_t)e * D_OUT + n0 + row) * D_IN + ss * 8;
    }

    int wm = wv >> 1, wn = wv & 1;
    int lm = lane & 15, q = lane >> 4;
    int l7 = lm & 7;                 // == (frag row)&7 for all frags

    floatx4 acc[4][4];
    #pragma unroll
    for (int mi = 0; mi < 4; ++mi)
        #pragma unroll
        for (int ni = 0; ni < 4; ++ni)
            acc[mi][ni] = (floatx4){0.f, 0.f, 0.f, 0.f};

    for (int it = 0; it < D_IN / 64; ++it) {
        if (it) __syncthreads();              // readers of prev tile done
        #pragma unroll
        for (int r = 0; r < 4; ++r) {
            gload_lds16(asrc[r], (char*)Ash + r * 4096 + wv * 1024);
            gload_lds16(bsrc[r], (char*)Bsh + r * 4096 + wv * 1024);
            asrc[r] += 64; bsrc[r] += 64;
        }
        __syncthreads();                      // vmcnt(0) drained by compiler

        #pragma unroll
        for (int kk = 0; kk < 2; ++kk) {
            int sw = ((((kk << 2) | q) ^ l7) << 3);   // swizzled k-slot, shorts
            short8 afr[4], bfr[4];
            #pragma unroll
            for (int f = 0; f < 4; ++f) {
                afr[f] = *(const short8*)(Ash + ((wm * 64 + f * 16 + lm) << 6) + sw);
                bfr[f] = *(const short8*)(Bsh + ((wn * 64 + f * 16 + lm) << 6) + sw);
            }
            #pragma unroll
            for (int mi = 0; mi < 4; ++mi)
                #pragma unroll
                for (int ni = 0; ni < 4; ++ni)
                    acc[mi][ni] = __builtin_amdgcn_mfma_f32_16x16x32_bf16(
                        afr[mi], bfr[ni], acc[mi][ni], 0, 0, 0);
        }
    }

    // epilogue: C/D layout col=lane&15, row=(lane>>4)*4+reg
    #pragma unroll
    for (int mi = 0; mi < 4; ++mi) {
        int rbase = wm * 64 + mi * 16 + q * 4;
        #pragma unroll
        for (int r = 0; r < 4; ++r) {
            int row = rbase + r;
            int gi = ty * 128 + row;
            bool ok = gi < n_e;
            int v = rid_sh[row];
            float g = gt_sh[row];
            size_t orow = (size_t)(v >> 1) * D_OUT;
            #pragma unroll
            for (int ni = 0; ni < 4; ++ni) {
                int c = n0 + wn * 64 + ni * 16 + lm;
                float val = g * __expf(acc[mi][ni][r]);
                if (ok) {
                    if (USE_CONTRIB) {
                        float* dst = (v & 1) ? contrib : out;
                        dst[orow + c] = val;
                    } else {
                        atomicAdd(&out[orow + c], val);
                    }
                }
            }
        }
    }
}

// ---------------------------------------------------------------------------
// Fallback f32-input GEMM (used only when ws too small for bf16 buffers).
// ---------------------------------------------------------------------------
template<bool USE_CONTRIB>
__global__ __launch_bounds__(256) void moe_gemm(
        const float* __restrict__ x, const float* __restrict__ w,
        const int* __restrict__ counts, const int* __restrict__ rowlist,
        const float* __restrict__ gatelist,
        float* __restrict__ out, float* __restrict__ contrib) {
    int e = blockIdx.z;
    int n_e = counts[e * CNT_STRIDE];
    int ty = blockIdx.y;
    if (ty * 128 >= n_e) return;
    int n0 = blockIdx.x * 128;

    __shared__ u16_t Ash[128][40];
    __shared__ u32_t Bsh[16][132];
    __shared__ int   rid_sh[128];
    __shared__ float gt_sh[128];

    int t = threadIdx.x;
    if (t < 128) {
        int gi = ty * 128 + t;
        int v = 0; float g = 0.f;
        if (gi < n_e) { v = rowlist[e * B_ROWS + gi]; g = gatelist[e * B_ROWS + gi]; }
        rid_sh[t] = v; gt_sh[t] = g;
    }
    __syncthreads();

    int ar = t >> 1, ah = t & 1;
    const float* xptr = x + (size_t)(rid_sh[ar] >> 1) * D_IN + ah * 16;
    int bkp = t >> 4, bng = t & 15;
    const float* wptr = w + (size_t)e * (D_IN * D_OUT)
                          + (size_t)(2 * bkp) * D_OUT + n0 + bng * 8;

    int lane = t & 63, wv = t >> 6;
    int wm = wv >> 1, wn = wv & 1;
    int lm = lane & 15, q = lane >> 4;

    floatx4 acc[4][4];
    #pragma unroll
    for (int mi = 0; mi < 4; ++mi)
        #pragma unroll
        for (int ni = 0; ni < 4; ++ni)
            acc[mi][ni] = (floatx4){0.f, 0.f, 0.f, 0.f};

    for (int it = 0; it < D_IN / 32; ++it) {
        float4 av0 = *(const float4*)(xptr + 0);
        float4 av1 = *(const float4*)(xptr + 4);
        float4 av2 = *(const float4*)(xptr + 8);
        float4 av3 = *(const float4*)(xptr + 12);
        xptr += 32;
        float4 b0 = *(const float4*)(wptr + 0);
        float4 b1 = *(const float4*)(wptr + 4);
        float4 b2 = *(const float4*)(wptr + D_OUT);
        float4 b3 = *(const float4*)(wptr + D_OUT + 4);
        wptr += 32 * D_OUT;

        __syncthreads();
        {
            union { u16_t us[16]; uint4 v[2]; } ap;
            float af[16] = {av0.x, av0.y, av0.z, av0.w, av1.x, av1.y, av1.z, av1.w,
                            av2.x, av2.y, av2.z, av2.w, av3.x, av3.y, av3.z, av3.w};
            #pragma unroll
            for (int j = 0; j < 16; ++j) ap.us[j] = f2bf(af[j]);
            *(uint4*)(&Ash[ar][ah * 16])     = ap.v[0];
            *(uint4*)(&Ash[ar][ah * 16 + 8]) = ap.v[1];
        }
        {
            union { u32_t up[8]; uint4 v[2]; } bp;
            bp.up[0] = (u32_t)f2bf(b0.x) | ((u32_t)f2bf(b2.x) << 16);
            bp.up[1] = (u32_t)f2bf(b0.y) | ((u32_t)f2bf(b2.y) << 16);
            bp.up[2] = (u32_t)f2bf(b0.z) | ((u32_t)f2bf(b2.z) << 16);
            bp.up[3] = (u32_t)f2bf(b0.w) | ((u32_t)f2bf(b2.w) << 16);
            bp.up[4] = (u32_t)f2bf(b1.x) | ((u32_t)f2bf(b3.x) << 16);
            bp.up[5] = (u32_t)f2bf(b1.y) | ((u32_t)f2bf(b3.y) << 16);
            bp.up[6] = (u32_t)f2bf(b1.z) | ((u32_t)f2bf(b3.z) << 16);
            bp.up[7] = (u32_t)f2bf(b1.w) | ((u32_t)f2bf(b3.w) << 16);
            *(uint4*)(&Bsh[bkp][bng * 8])     = bp.v[0];
            *(uint4*)(&Bsh[bkp][bng * 8 + 4]) = bp.v[1];
        }
        __syncthreads();

        short8 afr[4];
        #pragma unroll
        for (int mi = 0; mi < 4; ++mi)
            afr[mi] = *(const short8*)(&Ash[wm * 64 + mi * 16 + lm][q * 8]);
        short8 bfr[4];
        #pragma unroll
        for (int ni = 0; ni < 4; ++ni) {
            int nn = wn * 64 + ni * 16 + lm;
            union { uint4 u; short8 s; } cv;
            cv.u.x = Bsh[q * 4 + 0][nn];
            cv.u.y = Bsh[q * 4 + 1][nn];
            cv.u.z = Bsh[q * 4 + 2][nn];
            cv.u.w = Bsh[q * 4 + 3][nn];
            bfr[ni] = cv.s;
        }
        #pragma unroll
        for (int mi = 0; mi < 4; ++mi)
            #pragma unroll
            for (int ni = 0; ni < 4; ++ni)
                acc[mi][ni] = __builtin_amdgcn_mfma_f32_16x16x32_bf16(
                    afr[mi], bfr[ni], acc[mi][ni], 0, 0, 0);
    }

    #pragma unroll
    for (int mi = 0; mi < 4; ++mi) {
        int rbase = wm * 64 + mi * 16 + q * 4;
        #pragma unroll
        for (int r = 0; r < 4; ++r) {
            int row = rbase + r;
            int gi = ty * 128 + row;
            bool ok = gi < n_e;
            int v = rid_sh[row];
            float g = gt_sh[row];
            size_t orow = (size_t)(v >> 1) * D_OUT;
            #pragma unroll
            for (int ni = 0; ni < 4; ++ni) {
                int c = n0 + wn * 64 + ni * 16 + lm;
                float val = g * __expf(acc[mi][ni][r]);
                if (ok) {
                    if (USE_CONTRIB) {
                        float* dst = (v & 1) ? contrib : out;
                        dst[orow + c] = val;
                    } else {
                        atomicAdd(&out[orow + c], val);
                    }
                }
            }
        }
    }
}

// ---------------------------------------------------------------------------
// Combine: out = log(clamp(slot0 + slot1, eps))
// ---------------------------------------------------------------------------
__global__ __launch_bounds__(256) void combine_add_log(
        float* __restrict__ out, const float* __restrict__ contrib, int n4) {
    int i = blockIdx.x * blockDim.x + threadIdx.x;
    if (i >= n4) return;
    float4 a = ((const float4*)out)[i];
    float4 b = ((const float4*)contrib)[i];
    float4 r;
    float s;
    s = a.x + b.x; s = (s == 0.f) ? EPSF : s; r.x = __logf(s);
    s = a.y + b.y; s = (s == 0.f) ? EPSF : s; r.y = __logf(s);
    s = a.z + b.z; s = (s == 0.f) ? EPSF : s; r.z = __logf(s);
    s = a.w + b.w; s = (s == 0.f) ? EPSF : s; r.w = __logf(s);
    ((float4*)out)[i] = r;
}

__global__ __launch_bounds__(256) void log_inplace(float* __restrict__ out, int n4) {
    int i = blockIdx.x * blockDim.x + threadIdx.x;
    if (i >= n4) return;
    float4 a = ((float4*)out)[i];
    float4 r;
    float s;
    s = a.x; s = (s == 0.f) ? EPSF : s; r.x = __logf(s);
    s = a.y; s = (s == 0.f) ? EPSF : s; r.y = __logf(s);
    s = a.z; s = (s == 0.f) ? EPSF : s; r.z = __logf(s);
    s = a.w; s = (s == 0.f) ? EPSF : s; r.w = __logf(s);
    ((float4*)out)[i] = r;
}

extern "C" void kernel_launch(void* const* d_in, const int* in_sizes, int n_in,
                              void* d_out, int out_size, void* d_ws, size_t ws_size,
                              hipStream_t stream) {
    const float* x  = (const float*)d_in[0];
    const float* wr = (const float*)d_in[1];
    const float* we = (const float*)d_in[2];
    float* out = (float*)d_out;
    char* ws = (char*)d_ws;

    size_t off = 0;
    int*   counts  = (int*)(ws + off);   off += 1024;                 // 16 x 64B lines
    int*   rowlist = (int*)(ws + off);   off += (size_t)NEXP * B_ROWS * 4;
    float* gates   = (float*)(ws + off); off += (size_t)NEXP * B_ROWS * 4;
    float* wrT     = (float*)(ws + off); off += (size_t)NEXP * D_IN * 4;
    float* contrib = (float*)(ws + off); off += (size_t)B_ROWS * D_OUT * 4;
    size_t tier2_need = off;
    u16_t* xb      = (u16_t*)(ws + off); off += (size_t)B_ROWS * D_IN * 2;
    u16_t* wTb     = (u16_t*)(ws + off); off += (size_t)NEXP * D_IN * D_OUT * 2;
    size_t tier3_need = off;

    bool tier3 = ws_size >= tier3_need;
    bool tier2 = ws_size >= tier2_need;

    // prep: transpose wrT + zero counts (+ bf16 expert weights when tier3)
    prep_kernel<<<tier3 ? (65 + NEXP * 256) : 65, 256, 0, stream>>>(
        wr, wrT, we, wTb, counts);
    // router (+ fused x->bf16 conversion when tier3)
    router_kernel<<<B_ROWS / 16, 256, 0, stream>>>(
        x, wrT, counts, rowlist, gates, tier3 ? xb : (u16_t*)nullptr);

    int n4 = B_ROWS * D_OUT / 4;

    if (tier3) {
        moe_gemm_bf16<true><<<8192, 256, 0, stream>>>(
            xb, wTb, counts, rowlist, gates, out, contrib);
        combine_add_log<<<(n4 + 255) / 256, 256, 0, stream>>>(out, contrib, n4);
    } else if (tier2) {
        dim3 g(D_OUT / 128, B_ROWS / 128, NEXP);
        moe_gemm<true><<<g, 256, 0, stream>>>(x, we, counts, rowlist, gates, out, contrib);
        combine_add_log<<<(n4 + 255) / 256, 256, 0, stream>>>(out, contrib, n4);
    } else {
        dim3 g(D_OUT / 128, B_ROWS / 128, NEXP);
        hipMemsetAsync(out, 0, (size_t)B_ROWS * D_OUT * 4, stream);
        moe_gemm<false><<<g, 256, 0, stream>>>(x, we, counts, rowlist, gates, out, nullptr);
        log_inplace<<<(n4 + 255) / 256, 256, 0, stream>>>(out, n4);
    }
}

// Round 12
// 225.197 us; speedup vs baseline: 1.0416x; 1.0416x over previous
//
#include <hip/hip_runtime.h>
#include <hip/hip_bf16.h>
#include <stdint.h>

typedef unsigned short u16_t;
typedef unsigned int   u32_t;

#define B_ROWS  16384
#define D_IN    1024
#define D_OUT   512
#define NEXP    16
#define CNT_STRIDE 16   // pad each expert counter to its own 64B line
#define EPSF    2.2204460492503131e-16f

using short8  = __attribute__((ext_vector_type(8))) short;
using floatx4 = __attribute__((ext_vector_type(4))) float;

__device__ __forceinline__ u16_t f2bf(float f) {
    u32_t u = __float_as_uint(f);
    u += 0x7fffu + ((u >> 16) & 1u);        // round-to-nearest-even
    return (u16_t)(u >> 16);
}

// async global->LDS, 16B per lane. Global addr is per-lane; LDS dest is the
// wave-uniform base (HW adds lane*16).
__device__ __forceinline__ void gload_lds16(const void* g, void* l) {
    __builtin_amdgcn_global_load_lds(
        (const __attribute__((address_space(1))) void*)g,
        (__attribute__((address_space(3))) void*)l, 16, 0, 0);
}

// ---------------------------------------------------------------------------
// Prep: [0..63] transpose w_router -> wrT [E][D_IN] f32; [64] zero counts;
// [65..576] w_experts [e][k][n] f32 -> wT [e][n][k] bf16 via LDS-tiled
// transpose (R12 fix): the old direct store put each lane's 16B at stride
// 2048B -> every store touched its own 64B line = 4x write amplification
// (32MB -> ~128MB HBM writes). New scheme: per block (e, 64-n, 256-k),
// 8 iters of {load 32k x 64n coalesced, bf16-convert into LDS [32][80],
// write with (n=t>>2, kq=t&3): 4 lanes = one FULL aligned 64B line per n}.
// Output bytes identical to the old layout.
// ---------------------------------------------------------------------------
__global__ __launch_bounds__(256) void prep_kernel(
        const float* __restrict__ wr, float* __restrict__ wrT,
        const float* __restrict__ we, u16_t* __restrict__ wT,
        int* __restrict__ counts) {
    int b = blockIdx.x, t = threadIdx.x;
    if (b < 64) {
        int i = b * 256 + t;                 // i = e*D_IN + d
        int e = i >> 10, d = i & 1023;
        wrT[i] = wr[d * NEXP + e];
    } else if (b == 64) {
        counts[t] = 0;                       // 256 ints = 1024 B
    } else {
        __shared__ u16_t lsh[32 * 80];       // 32 k-rows x 80 u16 (16B-aligned)
        int bb = b - 65;                     // [0,512)
        int e  = bb >> 5;
        int nt = (bb & 31) >> 2, kt = bb & 3;
        int n0 = nt * 64, k0 = kt * 256;
        int kk = t >> 3, nf = t & 7;         // load map: 32 k x 8 n-octs
        int nn = t >> 2, kq = t & 3;         // write map: 64 n x 4 k-quads
        for (int it = 0; it < 8; ++it) {
            const float* src = we + ((size_t)e * D_IN + k0 + it * 32 + kk) * D_OUT
                                  + n0 + nf * 8;
            float4 a = *(const float4*)(src);
            float4 c = *(const float4*)(src + 4);
            union { u16_t us[8]; uint4 v; } p;
            p.us[0] = f2bf(a.x); p.us[1] = f2bf(a.y);
            p.us[2] = f2bf(a.z); p.us[3] = f2bf(a.w);
            p.us[4] = f2bf(c.x); p.us[5] = f2bf(c.y);
            p.us[6] = f2bf(c.z); p.us[7] = f2bf(c.w);
            if (it) __syncthreads();         // prev iter's readers done
            *(uint4*)(&lsh[kk * 80 + nf * 8]) = p.v;
            __syncthreads();
            union { u16_t us[8]; uint4 v; } q;
            #pragma unroll
            for (int j = 0; j < 8; ++j) q.us[j] = lsh[(kq * 8 + j) * 80 + nn];
            // 4 lanes (kq=0..3) cover one full aligned 64B line of row n
            *(uint4*)(wT + ((size_t)e * D_OUT + n0 + nn) * D_IN
                         + k0 + it * 32 + kq * 8) = q.v;
        }
    }
}

// ---------------------------------------------------------------------------
// Router v10 (round-9 best: 60us, VGPR 52 — reverted verbatim after v11's
// pin experiment regressed to 90us at VGPR 196 / 10% occupancy).
// f32 dot (ref logits are themselves f32); 32KB 2-phase expert-split w LDS
// (4 blk/CU), 8 rows/block, 2048 blocks, 32-lane butterfly, hierarchical
// atomics, fused x->bf16 emit (256B-contiguous per row per instr).
// ---------------------------------------------------------------------------
__global__ __launch_bounds__(256) void router_kernel(
        const float* __restrict__ x, const float* __restrict__ wrT,
        int* __restrict__ counts, int* __restrict__ rowlist,
        float* __restrict__ gatelist, u16_t* __restrict__ xb) {
    __shared__ float wsh[8 * D_IN];         // 32 KB: one 8-expert phase
    __shared__ int hist[NEXP], base[NEXP], hist2[NEXP];
    __shared__ unsigned char eidx_sh[8][2];
    __shared__ float g_sh[8][2];

    int t = threadIdx.x;
    if (t < NEXP) { hist[t] = 0; hist2[t] = 0; }

    int lane = t & 63, wv = t >> 6;
    int lr = t >> 5, c = t & 31;            // row group, d-slice
    int row = blockIdx.x * 8 + lr;

    // phase-A w stage (experts 0..7): async, 8 rounds x 1KB/wave, no VGPRs
    #pragma unroll
    for (int r = 0; r < 8; ++r) {
        int i = r * 256 + wv * 64 + lane;   // f4-slot in [0,2048)
        gload_lds16(wrT + (size_t)i * 4, (char*)wsh + r * 4096 + wv * 1024);
    }

    // x strip hoist: 8 independent HBM loads, then pin.
    const float* xr = x + (size_t)row * D_IN + c * 4;
    float4 xv[8];
    #pragma unroll
    for (int i = 0; i < 8; ++i) xv[i] = *(const float4*)(xr + i * 128);
    #pragma unroll
    for (int i = 0; i < 8; ++i)
        asm volatile("" :: "v"(xv[i].x), "v"(xv[i].y), "v"(xv[i].z), "v"(xv[i].w));

    if (xb) {                               // fused f32->bf16 emit, 256B/row/instr
        #pragma unroll
        for (int i = 0; i < 8; ++i) {
            uint2 pk;
            pk.x = (u32_t)f2bf(xv[i].x) | ((u32_t)f2bf(xv[i].y) << 16);
            pk.y = (u32_t)f2bf(xv[i].z) | ((u32_t)f2bf(xv[i].w) << 16);
            *(uint2*)(xb + (size_t)row * D_IN + c * 4 + i * 128) = pk;
        }
    }

    float acc[NEXP];
    #pragma unroll
    for (int e = 0; e < NEXP; ++e) acc[e] = 0.f;

    __syncthreads();                        // phase-A wsh ready (+hist init)
    #pragma unroll
    for (int i = 0; i < 8; ++i) {
        int fo = c * 4 + i * 128;           // float offset within an expert row
        float x0 = xv[i].x, x1 = xv[i].y, x2 = xv[i].z, x3 = xv[i].w;
        #pragma unroll
        for (int e = 0; e < 8; ++e) {
            float4 wv4 = *(const float4*)(&wsh[e * D_IN + fo]);
            acc[e] += x0 * wv4.x;
            acc[e] += x1 * wv4.y;
            acc[e] += x2 * wv4.z;
            acc[e] += x3 * wv4.w;
        }
    }
    __syncthreads();                        // all waves done reading phase A
    #pragma unroll
    for (int r = 0; r < 8; ++r) {           // phase-B stage (experts 8..15)
        int i = r * 256 + wv * 64 + lane;
        gload_lds16(wrT + 8192 + (size_t)i * 4, (char*)wsh + r * 4096 + wv * 1024);
    }
    __syncthreads();                        // phase-B wsh ready
    #pragma unroll
    for (int i = 0; i < 8; ++i) {
        int fo = c * 4 + i * 128;
        float x0 = xv[i].x, x1 = xv[i].y, x2 = xv[i].z, x3 = xv[i].w;
        #pragma unroll
        for (int e = 8; e < NEXP; ++e) {
            float4 wv4 = *(const float4*)(&wsh[(e - 8) * D_IN + fo]);
            acc[e] += x0 * wv4.x;
            acc[e] += x1 * wv4.y;
            acc[e] += x2 * wv4.z;
            acc[e] += x3 * wv4.w;
        }
    }

    // butterfly reduce over the 32 d-slice lanes (c = low 5 lane bits)
    #pragma unroll
    for (int e = 0; e < NEXP; ++e) {
        acc[e] += __shfl_xor(acc[e], 1);
        acc[e] += __shfl_xor(acc[e], 2);
        acc[e] += __shfl_xor(acc[e], 4);
        acc[e] += __shfl_xor(acc[e], 8);
        acc[e] += __shfl_xor(acc[e], 16);
    }
    if (c == 0) {
        // top-2, stable (lower index wins ties) == jax.lax.top_k
        int i1 = 0; float v1 = acc[0];
        #pragma unroll
        for (int e = 1; e < NEXP; ++e) if (acc[e] > v1) { v1 = acc[e]; i1 = e; }
        int i2 = -1; float v2 = -3.0e38f;
        #pragma unroll
        for (int e = 0; e < NEXP; ++e) if (e != i1 && acc[e] > v2) { v2 = acc[e]; i2 = e; }
        float ed = expf(v2 - v1);           // <= 1
        float s = 1.0f + ed;
        eidx_sh[lr][0] = (unsigned char)i1; g_sh[lr][0] = 1.0f / s;
        eidx_sh[lr][1] = (unsigned char)i2; g_sh[lr][1] = ed / s;
        atomicAdd(&hist[i1], 1);
        atomicAdd(&hist[i2], 1);
    }
    __syncthreads();
    if (t < NEXP) base[t] = atomicAdd(&counts[t * CNT_STRIDE], hist[t]);
    __syncthreads();
    if (t < 16) {
        int r = t >> 1, sl = t & 1;
        int e = eidx_sh[r][sl];
        int pos = base[e] + atomicAdd(&hist2[e], 1);
        rowlist[e * B_ROWS + pos] = ((blockIdx.x * 8 + r) << 1) | sl;
        gatelist[e * B_ROWS + pos] = g_sh[r][sl];
    }
}

// ---------------------------------------------------------------------------
// Grouped expert GEMM, m97 structure: 128x128 tile, BK=64, 16B
// global_load_lds staging into linear LDS [128][64] bf16, XOR swizzle
// slot^=(row&7) applied to BOTH the staging global source and the ds_read
// (involution -> linear dest stays correct). 2x2 waves, 4x4 16x16x32 frags.
// 1-D grid with XCD-aware decode: bid%8 = XCD owns experts {2x, 2x+1} so
// each expert's 1 MB B-panel stays L2-resident and A-tiles are XCD-local.
// ---------------------------------------------------------------------------
template<bool USE_CONTRIB>
__global__ __launch_bounds__(256) void moe_gemm_bf16(
        const u16_t* __restrict__ xb, const u16_t* __restrict__ wT,
        const int* __restrict__ counts, const int* __restrict__ rowlist,
        const float* __restrict__ gatelist,
        float* __restrict__ out, float* __restrict__ contrib) {
    int bid = blockIdx.x;
    int s   = bid >> 3;                       // 0..1023
    int e   = ((bid & 7) << 1) | (s >> 9);    // 2 experts per XCD class
    s &= 511;
    int tx = s & 3, ty = s >> 2;
    int n_e = counts[e * CNT_STRIDE];
    if (ty * 128 >= n_e) return;
    int n0 = tx * 128;

    __shared__ u16_t Ash[128 * 64];   // linear [row][64k] bf16, 16 KB
    __shared__ u16_t Bsh[128 * 64];   // linear [n][64k]  bf16, 16 KB
    __shared__ int   rid_sh[128];
    __shared__ float gt_sh[128];

    int t = threadIdx.x;
    if (t < 128) {
        int gi = ty * 128 + t;
        int v = 0; float g = 0.f;
        if (gi < n_e) { v = rowlist[e * B_ROWS + gi]; g = gatelist[e * B_ROWS + gi]; }
        rid_sh[t] = v; gt_sh[t] = g;
    }
    __syncthreads();

    int lane = t & 63, wv = t >> 6;

    // staging geometry: round r covers bytes [r*4096 + wv*1024 + lane*16).
    // 16B-slot id i = r*256 + wv*64 + lane; row = i>>3; phys slot = i&7;
    // source fetches logical slot (i&7)^(row&7)  (pre-swizzled source).
    const u16_t* asrc[4];
    const u16_t* bsrc[4];
    #pragma unroll
    for (int r = 0; r < 4; ++r) {
        int i   = r * 256 + wv * 64 + lane;
        int row = i >> 3;
        int ss  = (i & 7) ^ (row & 7);
        asrc[r] = xb + (size_t)(rid_sh[row] >> 1) * D_IN + ss * 8;
        bsrc[r] = wT + ((size_t)e * D_OUT + n0 + row) * D_IN + ss * 8;
    }

    int wm = wv >> 1, wn = wv & 1;
    int lm = lane & 15, q = lane >> 4;
    int l7 = lm & 7;                 // == (frag row)&7 for all frags

    floatx4 acc[4][4];
    #pragma unroll
    for (int mi = 0; mi < 4; ++mi)
        #pragma unroll
        for (int ni = 0; ni < 4; ++ni)
            acc[mi][ni] = (floatx4){0.f, 0.f, 0.f, 0.f};

    for (int it = 0; it < D_IN / 64; ++it) {
        if (it) __syncthreads();              // readers of prev tile done
        #pragma unroll
        for (int r = 0; r < 4; ++r) {
            gload_lds16(asrc[r], (char*)Ash + r * 4096 + wv * 1024);
            gload_lds16(bsrc[r], (char*)Bsh + r * 4096 + wv * 1024);
            asrc[r] += 64; bsrc[r] += 64;
        }
        __syncthreads();                      // vmcnt(0) drained by compiler

        #pragma unroll
        for (int kk = 0; kk < 2; ++kk) {
            int sw = ((((kk << 2) | q) ^ l7) << 3);   // swizzled k-slot, shorts
            short8 afr[4], bfr[4];
            #pragma unroll
            for (int f = 0; f < 4; ++f) {
                afr[f] = *(const short8*)(Ash + ((wm * 64 + f * 16 + lm) << 6) + sw);
                bfr[f] = *(const short8*)(Bsh + ((wn * 64 + f * 16 + lm) << 6) + sw);
            }
            #pragma unroll
            for (int mi = 0; mi < 4; ++mi)
                #pragma unroll
                for (int ni = 0; ni < 4; ++ni)
                    acc[mi][ni] = __builtin_amdgcn_mfma_f32_16x16x32_bf16(
                        afr[mi], bfr[ni], acc[mi][ni], 0, 0, 0);
        }
    }

    // epilogue: C/D layout col=lane&15, row=(lane>>4)*4+reg
    #pragma unroll
    for (int mi = 0; mi < 4; ++mi) {
        int rbase = wm * 64 + mi * 16 + q * 4;
        #pragma unroll
        for (int r = 0; r < 4; ++r) {
            int row = rbase + r;
            int gi = ty * 128 + row;
            bool ok = gi < n_e;
            int v = rid_sh[row];
            float g = gt_sh[row];
            size_t orow = (size_t)(v >> 1) * D_OUT;
            #pragma unroll
            for (int ni = 0; ni < 4; ++ni) {
                int c = n0 + wn * 64 + ni * 16 + lm;
                float val = g * __expf(acc[mi][ni][r]);
                if (ok) {
                    if (USE_CONTRIB) {
                        float* dst = (v & 1) ? contrib : out;
                        dst[orow + c] = val;
                    } else {
                        atomicAdd(&out[orow + c], val);
                    }
                }
            }
        }
    }
}

// ---------------------------------------------------------------------------
// Fallback f32-input GEMM (used only when ws too small for bf16 buffers).
// ---------------------------------------------------------------------------
template<bool USE_CONTRIB>
__global__ __launch_bounds__(256) void moe_gemm(
        const float* __restrict__ x, const float* __restrict__ w,
        const int* __restrict__ counts, const int* __restrict__ rowlist,
        const float* __restrict__ gatelist,
        float* __restrict__ out, float* __restrict__ contrib) {
    int e = blockIdx.z;
    int n_e = counts[e * CNT_STRIDE];
    int ty = blockIdx.y;
    if (ty * 128 >= n_e) return;
    int n0 = blockIdx.x * 128;

    __shared__ u16_t Ash[128][40];
    __shared__ u32_t Bsh[16][132];
    __shared__ int   rid_sh[128];
    __shared__ float gt_sh[128];

    int t = threadIdx.x;
    if (t < 128) {
        int gi = ty * 128 + t;
        int v = 0; float g = 0.f;
        if (gi < n_e) { v = rowlist[e * B_ROWS + gi]; g = gatelist[e * B_ROWS + gi]; }
        rid_sh[t] = v; gt_sh[t] = g;
    }
    __syncthreads();

    int ar = t >> 1, ah = t & 1;
    const float* xptr = x + (size_t)(rid_sh[ar] >> 1) * D_IN + ah * 16;
    int bkp = t >> 4, bng = t & 15;
    const float* wptr = w + (size_t)e * (D_IN * D_OUT)
                          + (size_t)(2 * bkp) * D_OUT + n0 + bng * 8;

    int lane = t & 63, wv = t >> 6;
    int wm = wv >> 1, wn = wv & 1;
    int lm = lane & 15, q = lane >> 4;

    floatx4 acc[4][4];
    #pragma unroll
    for (int mi = 0; mi < 4; ++mi)
        #pragma unroll
        for (int ni = 0; ni < 4; ++ni)
            acc[mi][ni] = (floatx4){0.f, 0.f, 0.f, 0.f};

    for (int it = 0; it < D_IN / 32; ++it) {
        float4 av0 = *(const float4*)(xptr + 0);
        float4 av1 = *(const float4*)(xptr + 4);
        float4 av2 = *(const float4*)(xptr + 8);
        float4 av3 = *(const float4*)(xptr + 12);
        xptr += 32;
        float4 b0 = *(const float4*)(wptr + 0);
        float4 b1 = *(const float4*)(wptr + 4);
        float4 b2 = *(const float4*)(wptr + D_OUT);
        float4 b3 = *(const float4*)(wptr + D_OUT + 4);
        wptr += 32 * D_OUT;

        __syncthreads();
        {
            union { u16_t us[16]; uint4 v[2]; } ap;
            float af[16] = {av0.x, av0.y, av0.z, av0.w, av1.x, av1.y, av1.z, av1.w,
                            av2.x, av2.y, av2.z, av2.w, av3.x, av3.y, av3.z, av3.w};
            #pragma unroll
            for (int j = 0; j < 16; ++j) ap.us[j] = f2bf(af[j]);
            *(uint4*)(&Ash[ar][ah * 16])     = ap.v[0];
            *(uint4*)(&Ash[ar][ah * 16 + 8]) = ap.v[1];
        }
        {
            union { u32_t up[8]; uint4 v[2]; } bp;
            bp.up[0] = (u32_t)f2bf(b0.x) | ((u32_t)f2bf(b2.x) << 16);
            bp.up[1] = (u32_t)f2bf(b0.y) | ((u32_t)f2bf(b2.y) << 16);
            bp.up[2] = (u32_t)f2bf(b0.z) | ((u32_t)f2bf(b2.z) << 16);
            bp.up[3] = (u32_t)f2bf(b0.w) | ((u32_t)f2bf(b2.w) << 16);
            bp.up[4] = (u32_t)f2bf(b1.x) | ((u32_t)f2bf(b3.x) << 16);
            bp.up[5] = (u32_t)f2bf(b1.y) | ((u32_t)f2bf(b3.y) << 16);
            bp.up[6] = (u32_t)f2bf(b1.z) | ((u32_t)f2bf(b3.z) << 16);
            bp.up[7] = (u32_t)f2bf(b1.w) | ((u32_t)f2bf(b3.w) << 16);
            *(uint4*)(&Bsh[bkp][bng * 8])     = bp.v[0];
            *(uint4*)(&Bsh[bkp][bng * 8 + 4]) = bp.v[1];
        }
        __syncthreads();

        short8 afr[4];
        #pragma unroll
        for (int mi = 0; mi < 4; ++mi)
            afr[mi] = *(const short8*)(&Ash[wm * 64 + mi * 16 + lm][q * 8]);
        short8 bfr[4];
        #pragma unroll
        for (int ni = 0; ni < 4; ++ni) {
            int nn = wn * 64 + ni * 16 + lm;
            union { uint4 u; short8 s; } cv;
            cv.u.x = Bsh[q * 4 + 0][nn];
            cv.u.y = Bsh[q * 4 + 1][nn];
            cv.u.z = Bsh[q * 4 + 2][nn];
            cv.u.w = Bsh[q * 4 + 3][nn];
            bfr[ni] = cv.s;
        }
        #pragma unroll
        for (int mi = 0; mi < 4; ++mi)
            #pragma unroll
            for (int ni = 0; ni < 4; ++ni)
                acc[mi][ni] = __builtin_amdgcn_mfma_f32_16x16x32_bf16(
                    afr[mi], bfr[ni], acc[mi][ni], 0, 0, 0);
    }

    #pragma unroll
    for (int mi = 0; mi < 4; ++mi) {
        int rbase = wm * 64 + mi * 16 + q * 4;
        #pragma unroll
        for (int r = 0; r < 4; ++r) {
            int row = rbase + r;
            int gi = ty * 128 + row;
            bool ok = gi < n_e;
            int v = rid_sh[row];
            float g = gt_sh[row];
            size_t orow = (size_t)(v >> 1) * D_OUT;
            #pragma unroll
            for (int ni = 0; ni < 4; ++ni) {
                int c = n0 + wn * 64 + ni * 16 + lm;
                float val = g * __expf(acc[mi][ni][r]);
                if (ok) {
                    if (USE_CONTRIB) {
                        float* dst = (v & 1) ? contrib : out;
                        dst[orow + c] = val;
                    } else {
                        atomicAdd(&out[orow + c], val);
                    }
                }
            }
        }
    }
}

// ---------------------------------------------------------------------------
// Combine: out = log(clamp(slot0 + slot1, eps))
// ---------------------------------------------------------------------------
__global__ __launch_bounds__(256) void combine_add_log(
        float* __restrict__ out, const float* __restrict__ contrib, int n4) {
    int i = blockIdx.x * blockDim.x + threadIdx.x;
    if (i >= n4) return;
    float4 a = ((const float4*)out)[i];
    float4 b = ((const float4*)contrib)[i];
    float4 r;
    float s;
    s = a.x + b.x; s = (s == 0.f) ? EPSF : s; r.x = __logf(s);
    s = a.y + b.y; s = (s == 0.f) ? EPSF : s; r.y = __logf(s);
    s = a.z + b.z; s = (s == 0.f) ? EPSF : s; r.z = __logf(s);
    s = a.w + b.w; s = (s == 0.f) ? EPSF : s; r.w = __logf(s);
    ((float4*)out)[i] = r;
}

__global__ __launch_bounds__(256) void log_inplace(float* __restrict__ out, int n4) {
    int i = blockIdx.x * blockDim.x + threadIdx.x;
    if (i >= n4) return;
    float4 a = ((float4*)out)[i];
    float4 r;
    float s;
    s = a.x; s = (s == 0.f) ? EPSF : s; r.x = __logf(s);
    s = a.y; s = (s == 0.f) ? EPSF : s; r.y = __logf(s);
    s = a.z; s = (s == 0.f) ? EPSF : s; r.z = __logf(s);
    s = a.w; s = (s == 0.f) ? EPSF : s; r.w = __logf(s);
    ((float4*)out)[i] = r;
}

extern "C" void kernel_launch(void* const* d_in, const int* in_sizes, int n_in,
                              void* d_out, int out_size, void* d_ws, size_t ws_size,
                              hipStream_t stream) {
    const float* x  = (const float*)d_in[0];
    const float* wr = (const float*)d_in[1];
    const float* we = (const float*)d_in[2];
    float* out = (float*)d_out;
    char* ws = (char*)d_ws;

    size_t off = 0;
    int*   counts  = (int*)(ws + off);   off += 1024;                 // 16 x 64B lines
    int*   rowlist = (int*)(ws + off);   off += (size_t)NEXP * B_ROWS * 4;
    float* gates   = (float*)(ws + off); off += (size_t)NEXP * B_ROWS * 4;
    float* wrT     = (float*)(ws + off); off += (size_t)NEXP * D_IN * 4;
    float* contrib = (float*)(ws + off); off += (size_t)B_ROWS * D_OUT * 4;
    size_t tier2_need = off;
    u16_t* xb      = (u16_t*)(ws + off); off += (size_t)B_ROWS * D_IN * 2;
    u16_t* wTb     = (u16_t*)(ws + off); off += (size_t)NEXP * D_IN * D_OUT * 2;
    size_t tier3_need = off;

    bool tier3 = ws_size >= tier3_need;
    bool tier2 = ws_size >= tier2_need;

    // prep: transpose wrT + zero counts (+ bf16 expert weights when tier3)
    prep_kernel<<<tier3 ? (65 + 512) : 65, 256, 0, stream>>>(
        wr, wrT, we, wTb, counts);
    // router (+ fused x->bf16 conversion when tier3)
    router_kernel<<<B_ROWS / 8, 256, 0, stream>>>(
        x, wrT, counts, rowlist, gates, tier3 ? xb : (u16_t*)nullptr);

    int n4 = B_ROWS * D_OUT / 4;

    if (tier3) {
        moe_gemm_bf16<true><<<8192, 256, 0, stream>>>(
            xb, wTb, counts, rowlist, gates, out, contrib);
        combine_add_log<<<(n4 + 255) / 256, 256, 0, stream>>>(out, contrib, n4);
    } else if (tier2) {
        dim3 g(D_OUT / 128, B_ROWS / 128, NEXP);
        moe_gemm<true><<<g, 256, 0, stream>>>(x, we, counts, rowlist, gates, out, contrib);
        combine_add_log<<<(n4 + 255) / 256, 256, 0, stream>>>(out, contrib, n4);
    } else {
        dim3 g(D_OUT / 128, B_ROWS / 128, NEXP);
        hipMemsetAsync(out, 0, (size_t)B_ROWS * D_OUT * 4, stream);
        moe_gemm<false><<<g, 256, 0, stream>>>(x, we, counts, rowlist, gates, out, nullptr);
        log_inplace<<<(n4 + 255) / 256, 256, 0, stream>>>(out, n4);
    }
}